// Round 1
// baseline (137.705 us; speedup 1.0000x reference)
//
#include <hip/hip_runtime.h>

// DeepComplexRBF: 3 sequential layers of
//   dist_sq[i] = sum_j |y[j] - G[i,j]|^2 ; phi[i] = exp(-dist_sq/(2 s[i]))
//   y_new[o]   = sum_i W[o,i]*phi[i] + b[o]   (complex W, real phi)
// All planes stored as (2, rows, cols) fp32: real plane then imag plane.
// Memory-bound: 576 MB of G/W streamed once -> ~91 us floor at 6.3 TB/s.

#define INPUT_DIM 1024
#define HID 4096
#define OUT_DIM 1024

__device__ __forceinline__ float wave_reduce_sum(float v) {
#pragma unroll
    for (int off = 32; off > 0; off >>= 1) v += __shfl_down(v, off, 64);
    return v;
}

// Reduce two values across a 256-thread block (4 waves). Result valid in tid 0.
__device__ __forceinline__ void block_reduce2(float& a, float& b, float* sred) {
    a = wave_reduce_sum(a);
    b = wave_reduce_sum(b);
    const int lane = threadIdx.x & 63;
    const int wave = threadIdx.x >> 6;
    if (lane == 0) { sred[wave] = a; sred[4 + wave] = b; }
    __syncthreads();
    if (threadIdx.x == 0) {
        a = sred[0] + sred[1] + sred[2] + sred[3];
        b = sred[4] + sred[5] + sred[6] + sred[7];
    }
}

// One block (256 threads) per row i of G (I rows, Oprev cols).
// smem: y_re[Oprev], y_im[Oprev], red[8]
__global__ __launch_bounds__(256) void rbf_phi(
        const float* __restrict__ Gre, const float* __restrict__ Gim,
        const float* __restrict__ yre, const float* __restrict__ yim,
        const float* __restrict__ s, float* __restrict__ phi, int Oprev) {
    extern __shared__ float sm[];
    float* sy_re = sm;
    float* sy_im = sm + Oprev;
    float* sred  = sm + 2 * Oprev;

    // stage y into LDS (vectorized, coalesced)
    for (int j = threadIdx.x * 4; j < Oprev; j += blockDim.x * 4) {
        *(float4*)(sy_re + j) = *(const float4*)(yre + j);
        *(float4*)(sy_im + j) = *(const float4*)(yim + j);
    }
    __syncthreads();

    const int i = blockIdx.x;
    const float* gre = Gre + (size_t)i * Oprev;
    const float* gim = Gim + (size_t)i * Oprev;

    float acc = 0.f, acc2 = 0.f;  // two accumulators; combined in reduce
    for (int j = threadIdx.x * 4; j < Oprev; j += blockDim.x * 4) {
        float4 gr = *(const float4*)(gre + j);
        float4 gi = *(const float4*)(gim + j);
        float4 yr = *(const float4*)(sy_re + j);
        float4 yi = *(const float4*)(sy_im + j);
        float dr, di;
        dr = yr.x - gr.x; di = yi.x - gi.x; acc  += dr * dr + di * di;
        dr = yr.y - gr.y; di = yi.y - gi.y; acc2 += dr * dr + di * di;
        dr = yr.z - gr.z; di = yi.z - gi.z; acc  += dr * dr + di * di;
        dr = yr.w - gr.w; di = yi.w - gi.w; acc2 += dr * dr + di * di;
    }
    block_reduce2(acc, acc2, sred);
    if (threadIdx.x == 0) {
        float d = acc + acc2;
        phi[i] = expf(-d / (2.0f * s[i]));
    }
}

// One block (256 threads) per output row o of W (O rows, I cols).
// smem: phi[I], red[8]
__global__ __launch_bounds__(256) void rbf_w(
        const float* __restrict__ Wre, const float* __restrict__ Wim,
        const float* __restrict__ bre, const float* __restrict__ bim,
        const float* __restrict__ phi,
        float* __restrict__ out_re, float* __restrict__ out_im, int I) {
    extern __shared__ float sm[];
    float* sphi = sm;
    float* sred = sm + I;

    for (int j = threadIdx.x * 4; j < I; j += blockDim.x * 4)
        *(float4*)(sphi + j) = *(const float4*)(phi + j);
    __syncthreads();

    const int o = blockIdx.x;
    const float* wre = Wre + (size_t)o * I;
    const float* wim = Wim + (size_t)o * I;

    float ar = 0.f, ai = 0.f;
    for (int j = threadIdx.x * 4; j < I; j += blockDim.x * 4) {
        float4 wr = *(const float4*)(wre + j);
        float4 wi = *(const float4*)(wim + j);
        float4 p  = *(const float4*)(sphi + j);
        ar += wr.x * p.x + wr.y * p.y + wr.z * p.z + wr.w * p.w;
        ai += wi.x * p.x + wi.y * p.y + wi.z * p.z + wi.w * p.w;
    }
    block_reduce2(ar, ai, sred);
    if (threadIdx.x == 0) {
        out_re[o] = ar + bre[o];
        out_im[o] = ai + bim[o];
    }
}

extern "C" void kernel_launch(void* const* d_in, const int* in_sizes, int n_in,
                              void* d_out, int out_size, void* d_ws, size_t ws_size,
                              hipStream_t stream) {
    // inputs: x, W1,b1,G1,s1, W2,b2,G2,s2, W3,b3,G3,s3
    const float* x  = (const float*)d_in[0];
    const float* W1 = (const float*)d_in[1];
    const float* b1 = (const float*)d_in[2];
    const float* G1 = (const float*)d_in[3];
    const float* s1 = (const float*)d_in[4];
    const float* W2 = (const float*)d_in[5];
    const float* b2 = (const float*)d_in[6];
    const float* G2 = (const float*)d_in[7];
    const float* s2 = (const float*)d_in[8];
    const float* W3 = (const float*)d_in[9];
    const float* b3 = (const float*)d_in[10];
    const float* G3 = (const float*)d_in[11];
    const float* s3 = (const float*)d_in[12];
    float* out = (float*)d_out;  // (2, 1024)

    float* ws  = (float*)d_ws;
    float* phi = ws;            // 4096
    float* yre = ws + 4096;     // 4096
    float* yim = ws + 8192;     // 4096

    const int TB = 256;
    // Layer 1: I=4096, Oprev=1024, O=4096
    {
        const float* Gre = G1, *Gim = G1 + (size_t)HID * INPUT_DIM;
        rbf_phi<<<HID, TB, (2 * INPUT_DIM + 8) * sizeof(float), stream>>>(
            Gre, Gim, x, x + INPUT_DIM, s1, phi, INPUT_DIM);
        const float* Wre = W1, *Wim = W1 + (size_t)HID * HID;
        rbf_w<<<HID, TB, (HID + 8) * sizeof(float), stream>>>(
            Wre, Wim, b1, b1 + HID, phi, yre, yim, HID);
    }
    // Layer 2: I=4096, Oprev=4096, O=4096
    {
        const float* Gre = G2, *Gim = G2 + (size_t)HID * HID;
        rbf_phi<<<HID, TB, (2 * HID + 8) * sizeof(float), stream>>>(
            Gre, Gim, yre, yim, s2, phi, HID);
        const float* Wre = W2, *Wim = W2 + (size_t)HID * HID;
        rbf_w<<<HID, TB, (HID + 8) * sizeof(float), stream>>>(
            Wre, Wim, b2, b2 + HID, phi, yre, yim, HID);
    }
    // Layer 3: I=4096, Oprev=4096, O=1024
    {
        const float* Gre = G3, *Gim = G3 + (size_t)HID * HID;
        rbf_phi<<<HID, TB, (2 * HID + 8) * sizeof(float), stream>>>(
            Gre, Gim, yre, yim, s3, phi, HID);
        const float* Wre = W3, *Wim = W3 + (size_t)OUT_DIM * HID;
        rbf_w<<<OUT_DIM, TB, (HID + 8) * sizeof(float), stream>>>(
            Wre, Wim, b3, b3 + OUT_DIM, phi, out, out + OUT_DIM, HID);
    }
}